// Round 2
// baseline (18072.275 us; speedup 1.0000x reference)
//
#include <hip/hip_runtime.h>
#include <cstdint>

#define DEV __device__ __forceinline__

typedef unsigned short ushort8 __attribute__((ext_vector_type(8)));
typedef unsigned int uint32;

#if __has_builtin(__builtin_amdgcn_rcpf)
DEV float rcp_fast(float x) { return __builtin_amdgcn_rcpf(x); }
#else
DEV float rcp_fast(float x) { return 1.f / x; }
#endif

// tanh(x) = 1 - 2/(exp(2x)+1): safe at +/-inf (no NaN), ~1e-7 rel err.
DEV float tanh_fast(float x) {
  float z = __expf(2.f * x);
  return 1.f - 2.f * rcp_fast(z + 1.f);
}
DEV float sigmoid_fast(float x) {
  return rcp_fast(1.f + __expf(-x));
}

// bf16 helpers (RTN pack; unpack via bit shift).
DEV unsigned short f2bf(float f) {
  uint32 u = __float_as_uint(f);
  u += 0x7FFFu + ((u >> 16) & 1u);
  return (unsigned short)(u >> 16);
}
DEV float bf2f(unsigned short s) { return __uint_as_float(((uint32)s) << 16); }
DEV float bf2f_lo(uint32 u) { return __uint_as_float(u << 16); }
DEV float bf2f_hi(uint32 u) { return __uint_as_float(u & 0xFFFF0000u); }

// ---------------- prep: decoder cell weights -> bf16 -----------------------
__global__ __launch_bounds__(256) void k_prep(const float* __restrict__ RHw,
                                              const float* __restrict__ RTw,
                                              unsigned short* __restrict__ out) {
  int i = blockIdx.x * 256 + threadIdx.x;
  if (i < 49152) {
    out[i] = f2bf(RHw[i]);
    out[49152 + i] = f2bf(RTw[i]);
  }
}

// ---------------- conv0: [B,T,16] -> [B,T,64], k=5 pad=2, +bias, ReLU ------
__global__ __launch_bounds__(256) void k_conv0(
    const float* __restrict__ x, const float* __restrict__ w,
    const float* __restrict__ bias, float* __restrict__ out) {
  __shared__ float wl[16 * 5 * 64];
  __shared__ float xl[68 * 16];
  const int blk = blockIdx.x;
  const int b = blk >> 2, tt = blk & 3;
  const int tid = threadIdx.x;
  for (int i = tid; i < 5120; i += 256) {
    int o = i / 80, rem = i % 80, ii = rem / 5, kk = rem % 5;
    wl[(ii * 5 + kk) * 64 + o] = w[i];
  }
  const int t0 = tt * 64;
  for (int i = tid; i < 68 * 16; i += 256) {
    int row = i >> 4, c = i & 15;
    int t = t0 - 2 + row;
    xl[i] = (t >= 0 && t < 256) ? x[((b << 8) + t) * 16 + c] : 0.f;
  }
  __syncthreads();
  const int o = tid & 63, tr = tid >> 6;
  for (int j = 0; j < 16; ++j) {
    int tl = tr * 16 + j;
    float acc = bias[o];
#pragma unroll
    for (int kk = 0; kk < 5; ++kk)
#pragma unroll
      for (int ii = 0; ii < 16; ++ii)
        acc += xl[(tl + kk) * 16 + ii] * wl[(ii * 5 + kk) * 64 + o];
    out[((b << 8) + t0 + tl) * 64 + o] = fmaxf(acc, 0.f);
  }
}

// ---------------- conv1: [B,T,64] -> [B,T,64], k=5 pad=2, +bias, ReLU ------
__global__ __launch_bounds__(256) void k_conv1(
    const float* __restrict__ in0, const float* __restrict__ w,
    const float* __restrict__ bias, float* __restrict__ out) {
  __shared__ float wl[64 * 5 * 64];  // 80 KB
  __shared__ float xl[68 * 64];      // 17 KB
  const int blk = blockIdx.x;
  const int b = blk >> 2, tt = blk & 3;
  const int tid = threadIdx.x;
  for (int i = tid; i < 64 * 5 * 64; i += 256) {
    int o = i / 320, rem = i % 320, ii = rem / 5, kk = rem % 5;
    wl[(ii * 5 + kk) * 64 + o] = w[i];
  }
  const int t0 = tt * 64;
  for (int i = tid; i < 68 * 64; i += 256) {
    int row = i >> 6, c = i & 63;
    int t = t0 - 2 + row;
    xl[i] = (t >= 0 && t < 256) ? in0[((b << 8) + t) * 64 + c] : 0.f;
  }
  __syncthreads();
  const int o = tid & 63, tr = tid >> 6;
  for (int j = 0; j < 16; ++j) {
    int tl = tr * 16 + j;
    float acc = bias[o];
    for (int kk = 0; kk < 5; ++kk) {
#pragma unroll 16
      for (int ii = 0; ii < 64; ++ii)
        acc += xl[(tl + kk) * 64 + ii] * wl[(ii * 5 + kk) * 64 + o];
    }
    out[((b << 8) + t0 + tl) * 64 + o] = fmaxf(acc, 0.f);
  }
}

// --------- c2e (+bias) fused with encoder input projections x@WH, x@WT -----
__global__ __launch_bounds__(256) void k_c2e_proj(
    const float* __restrict__ in1, const float* __restrict__ cw,
    const float* __restrict__ cb, const float* __restrict__ WH,
    const float* __restrict__ WT, float* __restrict__ xph,
    float* __restrict__ xpt) {
  __shared__ float xin[64 * 64];
  __shared__ float w1[64 * 64];
  __shared__ float xe[64 * 64];
  __shared__ float wh[64 * 128];
  __shared__ float wt[64 * 128];
  const int blk = blockIdx.x;
  const int b = blk >> 2, tt = blk & 3;
  const int tid = threadIdx.x;
  for (int i = tid; i < 4096; i += 256) {
    xin[i] = in1[(size_t)(((b << 8) + tt * 64)) * 64 + i];
    w1[i] = cw[i];
  }
  for (int i = tid; i < 8192; i += 256) {
    wh[i] = WH[i];
    wt[i] = WT[i];
  }
  __syncthreads();
  {
    const int o = tid & 63, tr = tid >> 6;
    for (int j = 0; j < 16; ++j) {
      int tl = tr * 16 + j;
      float acc = cb[o];
#pragma unroll 16
      for (int k = 0; k < 64; ++k) acc += xin[tl * 64 + k] * w1[k * 64 + o];
      xe[tl * 64 + o] = acc;
    }
  }
  __syncthreads();
  {
    const int m = tid & 127, hf = tid >> 7;
    for (int j = 0; j < 32; ++j) {
      int tl = hf * 32 + j;
      float a0 = 0.f, a1 = 0.f;
#pragma unroll 16
      for (int k = 0; k < 64; ++k) {
        float xv = xe[tl * 64 + k];
        a0 += xv * wh[k * 128 + m];
        a1 += xv * wt[k * 128 + m];
      }
      size_t oidx = (size_t)((b << 8) + tt * 64 + tl) * 128 + m;
      xph[oidx] = a0;
      xpt[oidx] = a1;
    }
  }
}

// ---------------- encoder RHN: one block per batch row ---------------------
__global__ __launch_bounds__(512, 2) void k_encoder(
    const float* __restrict__ xph, const float* __restrict__ xpt,
    const float* __restrict__ RHw, const float* __restrict__ RHb,
    const float* __restrict__ RTw, const float* __restrict__ RTb,
    unsigned short* __restrict__ h_bf) {
  const int b = blockIdx.x;
  const int tid = threadIdx.x;
  const int g = tid >> 8;
  const int m = (tid >> 1) & 127;
  const int hf = tid & 1;
  const float* W = g ? RTw : RHw;
  const float* Bb = g ? RTb : RHb;
  const float* XP = g ? xpt : xph;
  float wreg[3][64];
#pragma unroll
  for (int l = 0; l < 3; ++l)
#pragma unroll
    for (int j = 0; j < 64; ++j)
      wreg[l][j] = W[(size_t)(l * 128 + hf * 64 + j) * 128 + m];
  float bias[3];
#pragma unroll
  for (int l = 0; l < 3; ++l) bias[l] = Bb[l * 128 + m];

  __shared__ float s_lds[128];
  __shared__ float hg[128];
  __shared__ float tg[128];
  if (tid < 128) s_lds[tid] = 0.f;
  __syncthreads();

  for (int t = 0; t < 256; ++t) {
    const float xp = XP[(size_t)((b << 8) + t) * 128 + m];
#pragma unroll
    for (int l = 0; l < 3; ++l) {
      float acc = (hf == 0) ? (bias[l] + (l == 0 ? xp : 0.f)) : 0.f;
      const float* sp = s_lds + hf * 64;
#pragma unroll
      for (int j = 0; j < 64; ++j) acc += sp[j] * wreg[l][j];
      float tot = acc + __shfl_xor(acc, 1);
      if (hf == 0) {
        if (g == 0) hg[m] = tanh_fast(tot);
        else        tg[m] = sigmoid_fast(tot);
      }
      __syncthreads();
      if (tid < 128) {
        float tv = tg[tid];
        float sn = hg[tid] * tv + (1.f - tv) * s_lds[tid];
        s_lds[tid] = sn;
        h_bf[((size_t)(b * 3 + l) * 256 + t) * 128 + tid] = f2bf(sn);
      }
      __syncthreads();
    }
  }
}

// ------ Uh_bf[b][r][t][m] = bf16( h[b][r][t][:] @ Uk_w[r] + Uk_b[r] ) ------
__global__ __launch_bounds__(256) void k_uh(
    const unsigned short* __restrict__ h_bf, const float* __restrict__ Uk_w,
    const float* __restrict__ Uk_b, unsigned short* __restrict__ Uh_bf) {
  __shared__ float wl[128 * 128];  // 64 KB
  __shared__ float hl[32 * 128];   // 16 KB
  const int blk = blockIdx.x;
  const int b = blk / 24;
  const int rem = blk % 24;
  const int r = rem >> 3, tt = rem & 7;
  const int tid = threadIdx.x;
  for (int i = tid; i < 16384; i += 256) wl[i] = Uk_w[(size_t)r * 16384 + i];
  const size_t hbase = ((size_t)(b * 3 + r) * 256 + tt * 32) * 128;
  const ushort8* hv = (const ushort8*)(h_bf + hbase);
  for (int i = tid; i < 512; i += 256) {
    ushort8 u = hv[i];
#pragma unroll
    for (int j = 0; j < 8; ++j) hl[i * 8 + j] = bf2f(u[j]);
  }
  __syncthreads();
  const int m = tid & 127, tr = tid >> 7;
  const float ub = Uk_b[r * 128 + m];
  for (int j = 0; j < 16; ++j) {
    int tl = tr * 16 + j;
    float acc = ub;
#pragma unroll 16
    for (int n = 0; n < 128; ++n) acc += hl[tl * 128 + n] * wl[n * 128 + m];
    Uh_bf[hbase + (size_t)tl * 128 + m] = f2bf(acc);
  }
}

// ---------------- attentive RHN decoder: one block per batch row -----------
// 768 threads. Uh[b] cached in registers (bf16, 64 VGPR). Tk in bf16 regs.
// d-phase reads bf16 h coalesced. Cell weights bf16 from L2, 3-way n-split.
__global__ __launch_bounds__(768, 3) void k_decoder(
    const float* __restrict__ y, const unsigned short* __restrict__ Uh_bf,
    const unsigned short* __restrict__ h_bf, const float* __restrict__ Tk_w,
    const float* __restrict__ vk_w, const float* __restrict__ vk_b,
    const float* __restrict__ Wt_w, const float* __restrict__ Vt_w,
    const float* __restrict__ Vt_b,
    const float* __restrict__ WHd, const float* __restrict__ WTd,
    const unsigned short* __restrict__ cellw,
    const float* __restrict__ RHb, const float* __restrict__ RTb,
    const float* __restrict__ W_w, const float* __restrict__ W_b,
    const float* __restrict__ V_w, const float* __restrict__ V_b,
    float* __restrict__ out) {
  const int b = blockIdx.x;
  const int tid = threadIdx.x;
  __shared__ float s_lds[128];
  __shared__ float Ts_lds[384];
  __shared__ float a_lds[768];
  __shared__ float d_lds[384];
  __shared__ float vk_lds[384];
  __shared__ float Vt_lds[384];
  __shared__ float dpart[12 * 128];
  __shared__ float cpart[6 * 128];
  __shared__ float hg[128];
  __shared__ float tg[128];
  __shared__ float red[32];
  __shared__ float ytil_lds;

  const int r3 = tid >> 8;          // 0..2 (wave-uniform)
  const int m2 = (tid >> 1) & 127;
  const int p2 = tid & 1;

  // Tk slice -> bf16 packed registers (32 VGPR).
  ushort8 tkp[8];
#pragma unroll
  for (int q = 0; q < 8; ++q) {
    ushort8 v;
#pragma unroll
    for (int j = 0; j < 8; ++j)
      v[j] = f2bf(Tk_w[(size_t)(r3 * 128 + p2 * 64 + q * 8 + j) * 128 + m2]);
    tkp[q] = v;
  }

  // Uh row for (r3, t_e) -> bf16 packed registers (64 VGPR), loaded once.
  const int t_e = tid & 255;
  ushort8 ureg[16];
  {
    const ushort8* up =
        (const ushort8*)(Uh_bf + ((size_t)(b * 3 + r3) * 256 + t_e) * 128);
#pragma unroll
    for (int q = 0; q < 16; ++q) ureg[q] = up[q];
  }

  for (int i = tid; i < 384; i += 768) {
    vk_lds[i] = vk_w[i];
    Vt_lds[i] = Vt_w[i];
  }
  if (tid < 128) s_lds[tid] = 0.f;
  __syncthreads();

  const float vkb = vk_b[r3];
  const int wv = tid >> 6;  // wave 0..11
  const int lane = tid & 63;
  // d-phase role: (r3, tq, mp)
  const int mp = tid & 63, tq = (tid >> 6) & 3;
  const unsigned short* hrow =
      h_bf + ((size_t)(b * 3 + r3) * 256 + tq * 64) * 128 + 2 * mp;
  // cell role: (third, gc, mc)
  const int third = tid >> 8, gc = (tid >> 7) & 1, mc = tid & 127;
  const int n0 = third * 43, n1 = (third == 2) ? 128 : (third * 43 + 43);
  const unsigned short* Wc = cellw + gc * 49152 + mc;

  for (int step = 0; step < 256; ++step) {
    // ---- Ts[r][m] = s @ Tk_w[r] ----
    {
      float acc = 0.f;
      const float* sp = s_lds + p2 * 64;
#pragma unroll
      for (int q = 0; q < 8; ++q) {
        ushort8 v = tkp[q];
#pragma unroll
        for (int j = 0; j < 8; ++j) acc += sp[q * 8 + j] * bf2f(v[j]);
      }
      float tot = acc + __shfl_xor(acc, 1);
      if (p2 == 0) Ts_lds[r3 * 128 + m2] = tot;
    }
    __syncthreads();
    // ---- e[r][t] = vk . tanh(Uh + Ts) + vk_b  (Uh from registers) ----
    {
      const float4* ts4 = (const float4*)(Ts_lds + r3 * 128);
      const float4* vk4 = (const float4*)(vk_lds + r3 * 128);
      float acc0 = 0.f, acc1 = 0.f;
#pragma unroll
      for (int q = 0; q < 16; ++q) {
        ushort8 u = ureg[q];
        float4 t0 = ts4[2 * q], t1 = ts4[2 * q + 1];
        float4 v0 = vk4[2 * q], v1 = vk4[2 * q + 1];
        acc0 += v0.x * tanh_fast(bf2f(u[0]) + t0.x);
        acc1 += v0.y * tanh_fast(bf2f(u[1]) + t0.y);
        acc0 += v0.z * tanh_fast(bf2f(u[2]) + t0.z);
        acc1 += v0.w * tanh_fast(bf2f(u[3]) + t0.w);
        acc0 += v1.x * tanh_fast(bf2f(u[4]) + t1.x);
        acc1 += v1.y * tanh_fast(bf2f(u[5]) + t1.y);
        acc0 += v1.z * tanh_fast(bf2f(u[6]) + t1.z);
        acc1 += v1.w * tanh_fast(bf2f(u[7]) + t1.w);
      }
      a_lds[r3 * 256 + t_e] = acc0 + acc1 + vkb;
    }
    __syncthreads();
    // ---- softmax over t (per r) ----
    {
      float e = a_lds[r3 * 256 + t_e];
      float mx = e;
#pragma unroll
      for (int off = 32; off; off >>= 1) mx = fmaxf(mx, __shfl_xor(mx, off));
      if (lane == 0) red[wv] = mx;
      __syncthreads();
      const int wb = r3 * 4;
      mx = fmaxf(fmaxf(red[wb], red[wb + 1]), fmaxf(red[wb + 2], red[wb + 3]));
      float p = __expf(e - mx);
      float sm = p;
#pragma unroll
      for (int off = 32; off; off >>= 1) sm += __shfl_xor(sm, off);
      if (lane == 0) red[16 + wv] = sm;
      __syncthreads();
      float den =
          red[16 + wb] + red[16 + wb + 1] + red[16 + wb + 2] + red[16 + wb + 3];
      a_lds[r3 * 256 + t_e] = p * rcp_fast(den);
    }
    __syncthreads();
    // ---- d[r][m] = sum_t alpha[r][t] * h[b][r][t][m]  (bf16 h, coalesced) --
    {
      const float4* ap4 = (const float4*)(a_lds + r3 * 256 + tq * 64);
      float d0 = 0.f, d1 = 0.f;
#pragma unroll 4
      for (int i4 = 0; i4 < 16; ++i4) {
        float4 a = ap4[i4];
        uint32 u0 = *(const uint32*)(hrow + (size_t)(4 * i4 + 0) * 128);
        uint32 u1 = *(const uint32*)(hrow + (size_t)(4 * i4 + 1) * 128);
        uint32 u2 = *(const uint32*)(hrow + (size_t)(4 * i4 + 2) * 128);
        uint32 u3 = *(const uint32*)(hrow + (size_t)(4 * i4 + 3) * 128);
        d0 += a.x * bf2f_lo(u0); d1 += a.x * bf2f_hi(u0);
        d0 += a.y * bf2f_lo(u1); d1 += a.y * bf2f_hi(u1);
        d0 += a.z * bf2f_lo(u2); d1 += a.z * bf2f_hi(u2);
        d0 += a.w * bf2f_lo(u3); d1 += a.w * bf2f_hi(u3);
      }
      dpart[(r3 * 4 + tq) * 128 + 2 * mp] = d0;
      dpart[(r3 * 4 + tq) * 128 + 2 * mp + 1] = d1;
    }
    __syncthreads();
    if (tid < 384) {
      const int rr = tid >> 7, mm = tid & 127;
      d_lds[tid] = dpart[(rr * 4 + 0) * 128 + mm] + dpart[(rr * 4 + 1) * 128 + mm] +
                   dpart[(rr * 4 + 2) * 128 + mm] + dpart[(rr * 4 + 3) * 128 + mm];
    }
    __syncthreads();
    // ---- y_til = y_t*Wt + d.Vt_w + Vt_b ----
    {
      float part = (tid < 384) ? d_lds[tid] * Vt_lds[tid] : 0.f;
#pragma unroll
      for (int off = 32; off; off >>= 1) part += __shfl_xor(part, off);
      if (lane == 0) red[wv] = part;
      __syncthreads();
      if (tid == 0) {
        float tot = red[0] + red[1] + red[2] + red[3] + red[4] + red[5];
        ytil_lds = y[(b << 8) + step] * Wt_w[0] + tot + Vt_b[0];
      }
      __syncthreads();
    }
    // ---- decoder RHN cell (3 micro-steps, bf16 weights, 3-way n-split) ----
    {
      const float ytil = ytil_lds;
#pragma unroll
      for (int l = 0; l < 3; ++l) {
        {
          float acc = 0.f;
          const unsigned short* wp = Wc + (size_t)(l * 128 + n0) * 128;
          for (int n = n0; n < n1; ++n) {
            acc += s_lds[n] * bf2f(*wp);
            wp += 128;
          }
          cpart[(third * 2 + gc) * 128 + mc] = acc;
        }
        __syncthreads();
        if (tid < 256) {
          const int g = tid >> 7, m = tid & 127;
          float acc = cpart[(0 + g) * 128 + m] + cpart[(2 + g) * 128 + m] +
                      cpart[(4 + g) * 128 + m] + (g ? RTb : RHb)[l * 128 + m];
          if (l == 0) acc += ytil * (g ? WTd : WHd)[m];
          if (g == 0) hg[m] = tanh_fast(acc);
          else        tg[m] = sigmoid_fast(acc);
        }
        __syncthreads();
        if (tid < 128) {
          float tv = tg[tid];
          s_lds[tid] = hg[tid] * tv + (1.f - tv) * s_lds[tid];
        }
        __syncthreads();
      }
    }
  }
  // ---- output head: out[b] = s.W_w + W_b + d.V_w + V_b ----
  if (tid < 64) {
    float acc = 0.f;
    for (int i = tid; i < 128; i += 64) acc += s_lds[i] * W_w[i];
    for (int k = tid; k < 384; k += 64) acc += d_lds[k] * V_w[k];
#pragma unroll
    for (int off = 32; off; off >>= 1) acc += __shfl_xor(acc, off);
    if (tid == 0) out[b] = acc + W_b[0] + V_b[0];
  }
}

extern "C" void kernel_launch(void* const* d_in, const int* in_sizes, int n_in,
                              void* d_out, int out_size, void* d_ws,
                              size_t ws_size, hipStream_t stream) {
  (void)in_sizes; (void)n_in; (void)out_size; (void)ws_size;
  const float* x    = (const float*)d_in[0];
  const float* y    = (const float*)d_in[1];
  const float* c0w  = (const float*)d_in[2];
  const float* c0b  = (const float*)d_in[3];
  const float* c1w  = (const float*)d_in[4];
  const float* c1b  = (const float*)d_in[5];
  const float* c2ew = (const float*)d_in[6];
  const float* c2eb = (const float*)d_in[7];
  const float* eWH  = (const float*)d_in[8];
  const float* eWT  = (const float*)d_in[9];
  const float* eRHw = (const float*)d_in[10];
  const float* eRHb = (const float*)d_in[11];
  const float* eRTw = (const float*)d_in[12];
  const float* eRTb = (const float*)d_in[13];
  const float* dWH  = (const float*)d_in[14];
  const float* dWT  = (const float*)d_in[15];
  const float* dRHw = (const float*)d_in[16];
  const float* dRHb = (const float*)d_in[17];
  const float* dRTw = (const float*)d_in[18];
  const float* dRTb = (const float*)d_in[19];
  const float* Tk   = (const float*)d_in[20];
  const float* Ukw  = (const float*)d_in[21];
  const float* Ukb  = (const float*)d_in[22];
  const float* vkw  = (const float*)d_in[23];
  const float* vkb  = (const float*)d_in[24];
  const float* Wtw  = (const float*)d_in[25];
  const float* Vtw  = (const float*)d_in[26];
  const float* Vtb  = (const float*)d_in[27];
  const float* Ww   = (const float*)d_in[28];
  const float* Wb   = (const float*)d_in[29];
  const float* Vw   = (const float*)d_in[30];
  const float* Vb   = (const float*)d_in[31];
  float* out = (float*)d_out;
  float* ws = (float*)d_ws;

  // Workspace layout (float units). Total 37,797,888 floats = 151.2 MB.
  // h_bf:   [0, 12582912)                (bf16, 50.3 MB)
  // Uh_bf:  [12582912, 25165824)         (bf16, 50.3 MB) — aliases xph/xpt,
  //         written by k_uh AFTER xph/xpt are dead (encoder consumed them).
  // xph:    [12582912, 20971520) fp32; xpt: [20971520, 29360128) fp32
  // c0o:    [29360128, 33554432); c1o: [33554432, 37748736)
  // cellw:  [37748736, 37797888)         (bf16 RHw||RTw, 196 KB)
  unsigned short* h_bf  = (unsigned short*)ws;
  unsigned short* Uh_bf = (unsigned short*)(ws + 12582912);
  float* xph = ws + 12582912;
  float* xpt = ws + 20971520;
  float* c0o = ws + 29360128;
  float* c1o = ws + 33554432;
  unsigned short* cellw = (unsigned short*)(ws + 37748736);

  k_prep<<<192, 256, 0, stream>>>(dRHw, dRTw, cellw);
  k_conv0<<<1024, 256, 0, stream>>>(x, c0w, c0b, c0o);
  k_conv1<<<1024, 256, 0, stream>>>(c0o, c1w, c1b, c1o);
  k_c2e_proj<<<1024, 256, 0, stream>>>(c1o, c2ew, c2eb, eWH, eWT, xph, xpt);
  k_encoder<<<256, 512, 0, stream>>>(xph, xpt, eRHw, eRHb, eRTw, eRTb, h_bf);
  k_uh<<<6144, 256, 0, stream>>>(h_bf, Ukw, Ukb, Uh_bf);
  k_decoder<<<256, 768, 0, stream>>>(y, Uh_bf, h_bf, Tk, vkw, vkb, Wtw, Vtw,
                                     Vtb, dWH, dWT, cellw, dRHb, dRTb,
                                     Ww, Wb, Vw, Vb, out);
}